// Round 9
// baseline (12149.023 us; speedup 1.0000x reference)
//
#include <hip/hip_runtime.h>

typedef _Float16 f16;
typedef _Float16 f16x8 __attribute__((ext_vector_type(8)));
typedef float    f32x4 __attribute__((ext_vector_type(4)));
typedef unsigned long long u64x2 __attribute__((ext_vector_type(2)));

#define SEQ   2048
#define BATCH 64
#define EMBED 256
#define HID   256
#define NC    1024            // 4 gates * HID
#define NWG   16              // recurrence workgroups (one island)

// fast transcendentals (1-instr HW ops)
__device__ __forceinline__ float fexp2(float x){ float r; asm("v_exp_f32 %0, %1" : "=v"(r) : "v"(x)); return r; }
__device__ __forceinline__ float frcp (float x){ float r; asm("v_rcp_f32 %0, %1" : "=v"(r) : "v"(x)); return r; }
__device__ __forceinline__ float sigm_f(float y){ return frcp(1.f + fexp2(y * -1.44269504f)); }
__device__ __forceinline__ float tanh_f(float y){ return 2.f*frcp(1.f + fexp2(y * -2.88539009f)) - 1.f; }

__device__ __forceinline__ void gload_lds4(const void* g, void* s) {
  __builtin_amdgcn_global_load_lds((const __attribute__((address_space(1))) void*)g,
                                   (__attribute__((address_space(3))) void*)s, 4, 0, 0);
}

// ---------------------------------------------------------------------------
// prep_w: Wx_t/Wh_t [1024 col][256 k] f16 transposed.
// ---------------------------------------------------------------------------
__global__ __launch_bounds__(256) void prep_w(
    const float* __restrict__ Wix, const float* __restrict__ Wih,
    const float* __restrict__ Wfx, const float* __restrict__ Wfh,
    const float* __restrict__ Wgx, const float* __restrict__ Wgh,
    const float* __restrict__ Wox, const float* __restrict__ Woh,
    f16* __restrict__ Wx_t, f16* __restrict__ Wh_t)
{
  int tid = blockIdx.x*256 + threadIdx.x;
  const float* WX[4] = {Wix, Wfx, Wgx, Wox};
  const float* WH[4] = {Wih, Wfh, Wgh, Woh};
  int which = tid >> 15;
  int j  = (tid >> 5) & 1023;
  int ko = tid & 31;
  const float* src = (which ? WH : WX)[j >> 8];
  int u = j & 255;
  f16x8 v;
  #pragma unroll
  for (int qq = 0; qq < 8; ++qq) v[qq] = (f16)src[(ko*8+qq)*HID + u];
  *(f16x8*)((which ? Wh_t : Wx_t) + (size_t)j*256 + ko*8) = v;
}

// ---------------------------------------------------------------------------
// gemm_x (unchanged, known-good)
// ---------------------------------------------------------------------------
__global__ __launch_bounds__(256) void gemm_x(
    const float* __restrict__ emb, const f16* __restrict__ Bt,
    const float* __restrict__ b0, const float* __restrict__ b1,
    const float* __restrict__ b2, const float* __restrict__ b3,
    f16* __restrict__ Xo)
{
  __shared__ f16 Al[64*256];
  __shared__ f16 Bl[64*256];
  int wg = blockIdx.x;
  int R0 = (wg >> 4) * 64;
  int C0 = (wg & 15) * 64;
  int tid = threadIdx.x;

  #pragma unroll
  for (int j = 0; j < 8; ++j) {
    int c = tid + j*256; int row = c >> 5, ci = c & 31;
    const float* ap = emb + (size_t)(R0+row)*EMBED + ci*8;
    f32x4 a0 = *(const f32x4*)ap;
    f32x4 a1 = *(const f32x4*)(ap + 4);
    f16x8 v;
    #pragma unroll
    for (int qq = 0; qq < 4; ++qq) { v[qq] = (f16)a0[qq]; v[qq+4] = (f16)a1[qq]; }
    *(f16x8*)((char*)Al + row*512 + ((ci*16) ^ ((row&7)<<4))) = v;
    f16x8 vb = *(const f16x8*)(Bt + (size_t)(C0+row)*256 + ci*8);
    *(f16x8*)((char*)Bl + row*512 + ((ci*16) ^ ((row&7)<<4))) = vb;
  }
  __syncthreads();

  int w = tid >> 6, l = tid & 63, lr = l & 15, lg = l >> 4;
  const float* bp = (C0 < 256) ? b0 : (C0 < 512) ? b1 : (C0 < 768) ? b2 : b3;
  int ub = (C0 & 255) + lr;
  f32x4 cf[4];
  #pragma unroll
  for (int nt = 0; nt < 4; ++nt) { float bv = bp[ub + nt*16]; cf[nt] = (f32x4){bv,bv,bv,bv}; }

  #pragma unroll
  for (int kf = 0; kf < 8; ++kf) {
    int arow = w*16 + lr;
    f16x8 af = *(const f16x8*)((char*)Al + arow*512 + ((kf*64 + lg*16) ^ ((arow&7)<<4)));
    #pragma unroll
    for (int nt = 0; nt < 4; ++nt) {
      int brow = nt*16 + lr;
      f16x8 bf = *(const f16x8*)((char*)Bl + brow*512 + ((kf*64 + lg*16) ^ ((brow&7)<<4)));
      cf[nt] = __builtin_amdgcn_mfma_f32_16x16x32_f16(af, bf, cf[nt], 0, 0, 0);
    }
  }
  #pragma unroll
  for (int nt = 0; nt < 4; ++nt)
    #pragma unroll
    for (int r = 0; r < 4; ++r) {
      int row = R0 + w*16 + lg*4 + r;
      int col = C0 + nt*16 + lr;
      Xo[(size_t)row*NC + col] = (f16)cf[nt][r];
    }
}

// ---------------------------------------------------------------------------
// lstm_rec: 16 WGs (ONE island), 512 thr (8 waves). BATCHED A: MFMA A rows =
// 16 batch elements (not h-replication) -> 16x weight reuse, 2048 MFMA/step
// total. WG q owns units [q*16,(q+1)*16) x 4 gates = 64 cols. Waves =
// (rt = w>>1: batch rowtile) x (gp = w&1: gate pair; gp0={i,f}, gp1={g,o}).
// Per wave: 2 coltiles x 8 kf = 16 MFMA; B-frags = 16 = 64 VGPR -- fits the
// empirically-hard 128 arch-VGPR cap (R3-R8 lesson) with room to spare.
// h state lives in GLOBAL hg[2][64][256] f16 (parity dbuf, pre-zeroed):
//   gather: per kf, 2 relaxed-agent u64 atomic loads -> A frag (R6 mechanism)
//   publish (gp0 lanes): swizzle-pack u32 -> atomic store, vmcnt(0), flag=t+1
//   poll (wave0): 16 flags >= t. Parity proof: overwrite of hg[t&1] happens
//   at step t+1 gated on flags>=t+1, which implies all reads of h(t) retired.
// Activations: gp1 computes tanh(g),sigm(o) -> act LDS; gp0 owns c/h update.
// x: parity-double LDS buffer, distance-1 prefetch via global_load_lds.
// ---------------------------------------------------------------------------
__global__ __launch_bounds__(512) __attribute__((amdgpu_waves_per_eu(2,2)))
void lstm_rec(f16* Wh_t, const f16* __restrict__ X,
              unsigned* flag, char* hgc, float* __restrict__ out)
{
  __shared__ f16   xbuf[2][4096];    // 16 KB: [parity][b*128B + g*32B + u'*2B]
  __shared__ float act[64][2][16];   // 8 KB: [b][tanh(g),sigm(o)][u']

  int q   = blockIdx.x;
  int tid = threadIdx.x;
  int w = tid >> 6, l = tid & 63, lr = l & 15, lg = l >> 4;
  int rt = w >> 1, gp = w & 1;

  // ---- prologue ----
  // x(0) prefetch: 2048 u32 slots; slot s: b=s>>5, c32=s&31 -> gate=c32>>3, u32i=c32&7
  #pragma unroll
  for (int p = 0; p < 4; ++p) {
    int s = p*512 + tid;
    int b = s >> 5, c32 = s & 31;
    gload_lds4(X + ((size_t)b)*NC + (c32>>3)*256 + q*16 + (c32&7)*2,
               (char*)xbuf + s*4);
  }
  // B-frags: 16 resident (gate gp*2+ci, units q*16+lr)
  f16x8 WB[2][8];
  #pragma unroll
  for (int ci = 0; ci < 2; ++ci) {
    int col = (gp*2+ci)*256 + q*16 + lr;
    f16* basep = Wh_t + (size_t)col*256 + lg*8;
    #pragma unroll
    for (int kf = 0; kf < 8; ++kf) WB[ci][kf] = *(f16x8*)(basep + kf*32);
  }
  #pragma unroll
  for (int ci = 0; ci < 2; ++ci)
    #pragma unroll
    for (int kf = 0; kf < 8; ++kf)
      asm volatile("" : "+v"(WB[ci][kf]));

  float cst[4] = {0.f, 0.f, 0.f, 0.f};

  asm volatile("s_waitcnt vmcnt(0) lgkmcnt(0)" ::: "memory");
  __builtin_amdgcn_s_barrier();

  for (int t = 0; t < SEQ; ++t) {
    int par = t & 1;
    // x prefetch t+1
    if (t + 1 < SEQ) {
      #pragma unroll
      for (int p = 0; p < 4; ++p) {
        int s = p*512 + tid;
        int b = s >> 5, c32 = s & 31;
        gload_lds4(X + ((size_t)(t+1)*BATCH + b)*NC + (c32>>3)*256 + q*16 + (c32&7)*2,
                   (char*)xbuf + (par^1)*8192 + s*4);
      }
    }
    // poll: everyone published h(t)
    if (w == 0) {
      unsigned tgt = (unsigned)t;
      for (;;) {
        unsigned ft = 0xFFFFFFFFu;
        if (l < NWG)
          ft = __hip_atomic_load(&flag[l], __ATOMIC_RELAXED, __HIP_MEMORY_SCOPE_AGENT);
        if (__all(ft >= tgt)) break;
      }
    }
    asm volatile("" ::: "memory");
    __builtin_amdgcn_s_barrier();                       // #1

    // cf init from x_t
    f32x4 cf[2];
    #pragma unroll
    for (int ci = 0; ci < 2; ++ci) {
      f32x4 v;
      #pragma unroll
      for (int r = 0; r < 4; ++r) {
        int b = rt*16 + lg*4 + r;
        f16 xv = *(const f16*)((const char*)xbuf + par*8192 + b*128 + (gp*2+ci)*32 + lr*2);
        v[r] = (float)xv;
      }
      cf[ci] = v;
    }
    // A gather (coherent u64 atomic loads) + MFMA; A: row=l&15 (batch), k=lg*8+j
    const char* hgp = hgc + (size_t)par*32768;
    #pragma unroll
    for (int kf = 0; kf < 8; ++kf) {
      size_t aoff = (size_t)(rt*16 + lr)*512 + kf*64 + lg*16;
      unsigned long long a0 = __hip_atomic_load((const unsigned long long*)(hgp + aoff),
                                                __ATOMIC_RELAXED, __HIP_MEMORY_SCOPE_AGENT);
      unsigned long long a1 = __hip_atomic_load((const unsigned long long*)(hgp + aoff + 8),
                                                __ATOMIC_RELAXED, __HIP_MEMORY_SCOPE_AGENT);
      f16x8 af = __builtin_bit_cast(f16x8, (u64x2){a0, a1});
      cf[0] = __builtin_amdgcn_mfma_f32_16x16x32_f16(af, WB[0][kf], cf[0], 0, 0, 0);
      cf[1] = __builtin_amdgcn_mfma_f32_16x16x32_f16(af, WB[1][kf], cf[1], 0, 0, 0);
    }
    // gp1: produce tanh(g), sigm(o) into act LDS
    if (gp == 1) {
      #pragma unroll
      for (int ci = 0; ci < 2; ++ci)
        #pragma unroll
        for (int r = 0; r < 4; ++r) {
          int b = rt*16 + lg*4 + r;
          float y = cf[ci][r];
          act[b][ci][lr] = (ci == 0) ? tanh_f(y) : sigm_f(y);
        }
    }
    asm volatile("s_waitcnt lgkmcnt(0)" ::: "memory");
    __builtin_amdgcn_s_barrier();                       // #2

    // gp0: c/h update + out + publish
    if (gp == 0) {
      char* hgn = hgc + (size_t)(par^1)*32768;
      #pragma unroll
      for (int r = 0; r < 4; ++r) {
        int b = rt*16 + lg*4 + r;
        float iv = sigm_f(cf[0][r]);
        float fv = sigm_f(cf[1][r]);
        float tg = act[b][0][lr];
        float so = act[b][1][lr];
        cst[r] = fv*cst[r] + iv*tg;
        float h = so * tanh_f(cst[r]);
        out[((size_t)t*BATCH + b)*HID + q*16 + lr] = h;
        f16 hf = (f16)h;
        unsigned lo = (unsigned)__builtin_bit_cast(unsigned short, hf);
        unsigned other = __builtin_amdgcn_ds_swizzle(lo, 0x041F);  // lane^1
        if ((l & 1) == 0) {
          unsigned pack = lo | (other << 16);
          __hip_atomic_store((unsigned*)(hgn + (size_t)b*512 + (q*16 + lr)*2), pack,
                             __ATOMIC_RELAXED, __HIP_MEMORY_SCOPE_AGENT);
        }
      }
      asm volatile("s_waitcnt vmcnt(0)" ::: "memory");  // drain publish (+out)
    }
    asm volatile("" ::: "memory");
    __builtin_amdgcn_s_barrier();                       // #3
    if (tid == 0)
      __hip_atomic_store(&flag[q], (unsigned)(t + 1),
                         __ATOMIC_RELAXED, __HIP_MEMORY_SCOPE_AGENT);
  }
}

// ---------------------------------------------------------------------------
extern "C" void kernel_launch(void* const* d_in, const int* in_sizes, int n_in,
                              void* d_out, int out_size, void* d_ws, size_t ws_size,
                              hipStream_t stream) {
  const float* emb = (const float*)d_in[0];
  const float* Wix = (const float*)d_in[1];
  const float* Wih = (const float*)d_in[2];
  const float* bi  = (const float*)d_in[3];
  const float* Wfx = (const float*)d_in[4];
  const float* Wfh = (const float*)d_in[5];
  const float* bf  = (const float*)d_in[6];
  const float* Wgx = (const float*)d_in[7];
  const float* Wgh = (const float*)d_in[8];
  const float* bg  = (const float*)d_in[9];
  const float* Wox = (const float*)d_in[10];
  const float* Woh = (const float*)d_in[11];
  const float* bo  = (const float*)d_in[12];

  char* ws = (char*)d_ws;
  f16*      Wx_t  = (f16*)(ws);                 //   524288 B
  f16*      Wh_t  = (f16*)(ws + 524288);        //   524288 B
  char*     hg    = ws + 1048576;               //    65536 B  [2][64][256] f16
  unsigned* flags = (unsigned*)(ws + 1114112);  //       64 B
  f16*      Xp    = (f16*)(ws + 1179648);       // 268435456 B

  hipMemsetAsync(ws + 1048576, 0, 65536 + 64, stream);
  prep_w  <<<256,   256, 0, stream>>>(Wix, Wih, Wfx, Wfh, Wgx, Wgh, Wox, Woh,
                                      Wx_t, Wh_t);
  gemm_x  <<<32768, 256, 0, stream>>>(emb, Wx_t, bi, bf, bg, bo, Xp);
  lstm_rec<<<NWG,   512, 0, stream>>>(Wh_t, Xp, flags, hg, (float*)d_out);
}

// Round 13
// 12103.172 us; speedup vs baseline: 1.0038x; 1.0038x over previous
//
#include <hip/hip_runtime.h>

typedef _Float16 f16;
typedef _Float16 f16x8 __attribute__((ext_vector_type(8)));
typedef float    f32x4 __attribute__((ext_vector_type(4)));
typedef unsigned long long u64x2 __attribute__((ext_vector_type(2)));

#define SEQ   2048
#define BATCH 64
#define EMBED 256
#define HID   256
#define NC    1024            // 4 gates * HID
#define FLSTR 32              // flag stride in u32 (128 B)

// fast transcendentals (1-instr HW ops)
__device__ __forceinline__ float fexp2(float x){ float r; asm("v_exp_f32 %0, %1" : "=v"(r) : "v"(x)); return r; }
__device__ __forceinline__ float frcp (float x){ float r; asm("v_rcp_f32 %0, %1" : "=v"(r) : "v"(x)); return r; }
__device__ __forceinline__ float sigm_f(float y){ return frcp(1.f + fexp2(y * -1.44269504f)); }
__device__ __forceinline__ float tanh_f(float y){ return 2.f*frcp(1.f + fexp2(y * -2.88539009f)) - 1.f; }

__device__ __forceinline__ void gload_lds16(const void* g, void* s) {
  __builtin_amdgcn_global_load_lds((const __attribute__((address_space(1))) void*)g,
                                   (__attribute__((address_space(3))) void*)s, 16, 0, 0);
}

// ---------------------------------------------------------------------------
// prep_w: Wx_t/Wh_t [1024 col][256 k] f16 transposed.
// ---------------------------------------------------------------------------
__global__ __launch_bounds__(256) void prep_w(
    const float* __restrict__ Wix, const float* __restrict__ Wih,
    const float* __restrict__ Wfx, const float* __restrict__ Wfh,
    const float* __restrict__ Wgx, const float* __restrict__ Wgh,
    const float* __restrict__ Wox, const float* __restrict__ Woh,
    f16* __restrict__ Wx_t, f16* __restrict__ Wh_t)
{
  int tid = blockIdx.x*256 + threadIdx.x;
  const float* WX[4] = {Wix, Wfx, Wgx, Wox};
  const float* WH[4] = {Wih, Wfh, Wgh, Woh};
  int which = tid >> 15;
  int j  = (tid >> 5) & 1023;
  int ko = tid & 31;
  const float* src = (which ? WH : WX)[j >> 8];
  int u = j & 255;
  f16x8 v;
  #pragma unroll
  for (int qq = 0; qq < 8; ++qq) v[qq] = (f16)src[(ko*8+qq)*HID + u];
  *(f16x8*)((which ? Wh_t : Wx_t) + (size_t)j*256 + ko*8) = v;
}

// ---------------------------------------------------------------------------
// gemm_x (unchanged, known-good)
// ---------------------------------------------------------------------------
__global__ __launch_bounds__(256) void gemm_x(
    const float* __restrict__ emb, const f16* __restrict__ Bt,
    const float* __restrict__ b0, const float* __restrict__ b1,
    const float* __restrict__ b2, const float* __restrict__ b3,
    f16* __restrict__ Xo)
{
  __shared__ f16 Al[64*256];
  __shared__ f16 Bl[64*256];
  int wg = blockIdx.x;
  int R0 = (wg >> 4) * 64;
  int C0 = (wg & 15) * 64;
  int tid = threadIdx.x;

  #pragma unroll
  for (int j = 0; j < 8; ++j) {
    int c = tid + j*256; int row = c >> 5, ci = c & 31;
    const float* ap = emb + (size_t)(R0+row)*EMBED + ci*8;
    f32x4 a0 = *(const f32x4*)ap;
    f32x4 a1 = *(const f32x4*)(ap + 4);
    f16x8 v;
    #pragma unroll
    for (int qq = 0; qq < 4; ++qq) { v[qq] = (f16)a0[qq]; v[qq+4] = (f16)a1[qq]; }
    *(f16x8*)((char*)Al + row*512 + ((ci*16) ^ ((row&7)<<4))) = v;
    f16x8 vb = *(const f16x8*)(Bt + (size_t)(C0+row)*256 + ci*8);
    *(f16x8*)((char*)Bl + row*512 + ((ci*16) ^ ((row&7)<<4))) = vb;
  }
  __syncthreads();

  int w = tid >> 6, l = tid & 63, lr = l & 15, lg = l >> 4;
  const float* bp = (C0 < 256) ? b0 : (C0 < 512) ? b1 : (C0 < 768) ? b2 : b3;
  int ub = (C0 & 255) + lr;
  f32x4 cf[4];
  #pragma unroll
  for (int nt = 0; nt < 4; ++nt) { float bv = bp[ub + nt*16]; cf[nt] = (f32x4){bv,bv,bv,bv}; }

  #pragma unroll
  for (int kf = 0; kf < 8; ++kf) {
    int arow = w*16 + lr;
    f16x8 af = *(const f16x8*)((char*)Al + arow*512 + ((kf*64 + lg*16) ^ ((arow&7)<<4)));
    #pragma unroll
    for (int nt = 0; nt < 4; ++nt) {
      int brow = nt*16 + lr;
      f16x8 bf = *(const f16x8*)((char*)Bl + brow*512 + ((kf*64 + lg*16) ^ ((brow&7)<<4)));
      cf[nt] = __builtin_amdgcn_mfma_f32_16x16x32_f16(af, bf, cf[nt], 0, 0, 0);
    }
  }
  #pragma unroll
  for (int nt = 0; nt < 4; ++nt)
    #pragma unroll
    for (int r = 0; r < 4; ++r) {
      int row = R0 + w*16 + lg*4 + r;
      int col = C0 + nt*16 + lr;
      Xo[(size_t)row*NC + col] = (f16)cf[nt][r];
    }
}

// ---------------------------------------------------------------------------
// lstm_rec: 16 WGs = 4 islands (bg) x 4 members (q).  [R12 bug: I launched 64
// WGs with bg in [0,16) => batches up to 255 (BATCH=64!) => OOB hg/out writes
// => core dump. 64/16 batches-per-island = 4 islands. Grid MUST be 16.]
// WG (bg,q): batches [bg*16,+16), cols = 4 gates x units [q*64,+64).
// Batched-A MFMA: A rows = the 16 island batches; B-frags register-resident
// (16 = 64 VGPR, under the hard 128 cap). Exchange = R9's proven protocol:
// relaxed agent atomics, parity-dbuf hg[2][64][256]f16, padded flags, ONLY
// vmcnt(0) drains (R10/R11: counted vmcnt over mixed load/store queues is
// unsafe — store acks vs load returns complete out of order).
// R13 refinements: out stores issued AFTER flag release (their HBM acks
// drain in next step's vmcnt(0), overlapped with poll+gather); act padded
// to [16][4][67] (odd stride -> worst 2-way LDS aliasing, free).
// ---------------------------------------------------------------------------
__global__ __launch_bounds__(512)
void lstm_rec(f16* Wh_t, const f16* __restrict__ X,
              unsigned* flag, char* hgc, float* __restrict__ out)
{
  __shared__ f16   xbuf[2][16][256];   // 16 KB: [parity][lb][cl]
  __shared__ float act[16][4][67];     // ~16.8 KB, odd-padded

  int bg = blockIdx.x >> 2, q = blockIdx.x & 3;   // bg in [0,4)
  int tid = threadIdx.x;
  int w = tid >> 6, l = tid & 63, lr = l & 15, lg = l >> 4;

  // ---- prologue ----
  // x(0): thread k stages 16 B: lb=k>>5, cl=(k&31)*8
  {
    int lb = tid >> 5, cl = (tid & 31)*8;
    int gcol = (cl >> 6)*256 + q*64 + (cl & 63);
    gload_lds16(X + (size_t)(bg*16 + lb)*NC + gcol, (char*)xbuf + tid*16);
  }
  // B-frags: wave w covers cols gate=w>>1, u''=(w&1)*32+ci*16+lr
  f16x8 WB[2][8];
  #pragma unroll
  for (int ci = 0; ci < 2; ++ci) {
    int col = (w>>1)*256 + q*64 + (w&1)*32 + ci*16 + lr;
    f16* basep = Wh_t + (size_t)col*256 + lg*8;
    #pragma unroll
    for (int kf = 0; kf < 8; ++kf) WB[ci][kf] = *(f16x8*)(basep + kf*32);
  }
  #pragma unroll
  for (int ci = 0; ci < 2; ++ci)
    #pragma unroll
    for (int kf = 0; kf < 8; ++kf)
      asm volatile("" : "+v"(WB[ci][kf]));

  float cstA = 0.f, cstB = 0.f;   // c for the 2 owned units
  int up_lb = tid >> 5;           // update ownership: local batch
  int up_u0 = (tid*2) & 63;       // first of 2 consecutive units

  asm volatile("s_waitcnt vmcnt(0) lgkmcnt(0)" ::: "memory");
  __builtin_amdgcn_s_barrier();

  for (int t = 0; t < SEQ; ++t) {
    int par = t & 1;
    // x prefetch t+1 (WAR-safe: target buffer last read at step t-1)
    if (t + 1 < SEQ) {
      int lb = tid >> 5, cl = (tid & 31)*8;
      int gcol = (cl >> 6)*256 + q*64 + (cl & 63);
      gload_lds16(X + ((size_t)(t+1)*BATCH + bg*16 + lb)*NC + gcol,
                  (char*)xbuf + (par^1)*8192 + tid*16);
    }
    // poll own island's 4 flags >= t
    if (w == 0) {
      unsigned tgt = (unsigned)t;
      for (;;) {
        unsigned ft = 0xFFFFFFFFu;
        if (l < 4)
          ft = __hip_atomic_load(&flag[(bg*4 + l)*FLSTR], __ATOMIC_RELAXED, __HIP_MEMORY_SCOPE_AGENT);
        if (__all(ft >= tgt)) break;
      }
    }
    asm volatile("" ::: "memory");
    __builtin_amdgcn_s_barrier();                       // #1

    // cf init from x_t: C row = lb = lg*4+r, local col cl = (2w+ci)*16+lr
    f32x4 cf[2];
    #pragma unroll
    for (int ci = 0; ci < 2; ++ci) {
      f32x4 v;
      #pragma unroll
      for (int r = 0; r < 4; ++r) {
        int lb = lg*4 + r;
        int cl = (2*w + ci)*16 + lr;
        v[r] = (float)xbuf[par][lb][cl];
      }
      cf[ci] = v;
    }
    // A gather (agent-scope u64 loads) + MFMA; A row = batch bg*16+lr, k=lg*8+j
    const char* hgp = hgc + (size_t)par*32768;
    #pragma unroll
    for (int kf = 0; kf < 8; ++kf) {
      size_t aoff = (size_t)(bg*16 + lr)*512 + kf*64 + lg*16;
      unsigned long long a0 = __hip_atomic_load((const unsigned long long*)(hgp + aoff),
                                                __ATOMIC_RELAXED, __HIP_MEMORY_SCOPE_AGENT);
      unsigned long long a1 = __hip_atomic_load((const unsigned long long*)(hgp + aoff + 8),
                                                __ATOMIC_RELAXED, __HIP_MEMORY_SCOPE_AGENT);
      f16x8 af = __builtin_bit_cast(f16x8, (u64x2){a0, a1});
      cf[0] = __builtin_amdgcn_mfma_f32_16x16x32_f16(af, WB[0][kf], cf[0], 0, 0, 0);
      cf[1] = __builtin_amdgcn_mfma_f32_16x16x32_f16(af, WB[1][kf], cf[1], 0, 0, 0);
    }
    // activations into act[lb][gate][u''] (wave: one gate, 32 units)
    {
      int g = w >> 1;
      #pragma unroll
      for (int ci = 0; ci < 2; ++ci) {
        int uu = (w&1)*32 + ci*16 + lr;
        #pragma unroll
        for (int r = 0; r < 4; ++r) {
          int lb = lg*4 + r;
          float y = cf[ci][r];
          act[lb][g][uu] = (g == 2) ? tanh_f(y) : sigm_f(y);
        }
      }
    }
    asm volatile("s_waitcnt lgkmcnt(0)" ::: "memory");
    __builtin_amdgcn_s_barrier();                       // #2

    // c/h update: thread owns (up_lb, up_u0) and (up_lb, up_u0+1)
    float h0, h1;
    {
      char* hgn = hgc + (size_t)(par^1)*32768;
      float i0 = act[up_lb][0][up_u0],   f0 = act[up_lb][1][up_u0];
      float g0 = act[up_lb][2][up_u0],   o0 = act[up_lb][3][up_u0];
      float i1 = act[up_lb][0][up_u0+1], f1 = act[up_lb][1][up_u0+1];
      float g1 = act[up_lb][2][up_u0+1], o1 = act[up_lb][3][up_u0+1];
      cstA = f0*cstA + i0*g0;
      cstB = f1*cstB + i1*g1;
      h0 = o0*tanh_f(cstA);
      h1 = o1*tanh_f(cstB);
      f16 hf0 = (f16)h0, hf1 = (f16)h1;
      unsigned pack = (unsigned)__builtin_bit_cast(unsigned short, hf0)
                    | ((unsigned)__builtin_bit_cast(unsigned short, hf1) << 16);
      __hip_atomic_store((unsigned*)(hgn + (size_t)(bg*16 + up_lb)*512 + (q*64 + up_u0)*2),
                         pack, __ATOMIC_RELAXED, __HIP_MEMORY_SCOPE_AGENT);
    }
    // full conservative drain (hg publishes + x prefetch) before flag release
    asm volatile("s_waitcnt vmcnt(0) lgkmcnt(0)" ::: "memory");
    __builtin_amdgcn_s_barrier();                       // #3
    if (tid == 0)
      __hip_atomic_store(&flag[(bg*4 + q)*FLSTR], (unsigned)(t + 1),
                         __ATOMIC_RELAXED, __HIP_MEMORY_SCOPE_AGENT);
    // out stores AFTER flag release: HBM acks drain in next step's vmcnt(0),
    // overlapped with poll+gather (they're protocol-irrelevant)
    {
      float2 o2 = {h0, h1};
      *(float2*)&out[((size_t)t*BATCH + bg*16 + up_lb)*HID + q*64 + up_u0] = o2;
    }
  }
}

// ---------------------------------------------------------------------------
extern "C" void kernel_launch(void* const* d_in, const int* in_sizes, int n_in,
                              void* d_out, int out_size, void* d_ws, size_t ws_size,
                              hipStream_t stream) {
  const float* emb = (const float*)d_in[0];
  const float* Wix = (const float*)d_in[1];
  const float* Wih = (const float*)d_in[2];
  const float* bi  = (const float*)d_in[3];
  const float* Wfx = (const float*)d_in[4];
  const float* Wfh = (const float*)d_in[5];
  const float* bf  = (const float*)d_in[6];
  const float* Wgx = (const float*)d_in[7];
  const float* Wgh = (const float*)d_in[8];
  const float* bg  = (const float*)d_in[9];
  const float* Wox = (const float*)d_in[10];
  const float* Woh = (const float*)d_in[11];
  const float* bo  = (const float*)d_in[12];

  char* ws = (char*)d_ws;
  f16*      Wx_t  = (f16*)(ws);                 //   524288 B
  f16*      Wh_t  = (f16*)(ws + 524288);        //   524288 B
  char*     hg    = ws + 1048576;               //    65536 B  [2][64][256] f16
  unsigned* flags = (unsigned*)(ws + 1114112);  //     8192 B
  f16*      Xp    = (f16*)(ws + 1179648);       // 268435456 B

  hipMemsetAsync(ws + 1048576, 0, 65536 + 8192, stream);
  prep_w  <<<256,   256, 0, stream>>>(Wix, Wih, Wfx, Wfh, Wgx, Wgh, Wox, Woh,
                                      Wx_t, Wh_t);
  gemm_x  <<<32768, 256, 0, stream>>>(emb, Wx_t, bi, bf, bg, bo, Xp);
  lstm_rec<<<16,    512, 0, stream>>>(Wh_t, Xp, flags, hg, (float*)d_out);
}